// Round 6
// baseline (5592.024 us; speedup 1.0000x reference)
//
#include <hip/hip_runtime.h>
#include <hip/hip_bf16.h>
#include <cstdint>
#include <cstddef>

// ---------- types ----------
typedef __bf16 bf16x8 __attribute__((ext_vector_type(8)));
typedef float  f32x4  __attribute__((ext_vector_type(4)));
typedef unsigned long long u64;

#define MFMA16(a, b, c) __builtin_amdgcn_mfma_f32_16x16x32_bf16((a), (b), (c), 0, 0, 0)

// async global->LDS, 16B per lane (wave-uniform base + lane*16 layout honored below)
#define ASYNC_CP16(gsrc, ldst)                                                              \
    __builtin_amdgcn_global_load_lds((const __attribute__((address_space(1))) void*)(gsrc), \
                                     (__attribute__((address_space(3))) void*)(ldst), 16, 0, 0)

// ---------- problem constants ----------
static constexpr int BN = 4, CN = 16, TN = 1000, FN = 96, HN = 64;
static constexpr int HID = 1536;          // C*F
static constexpr int INQ = 6144;          // H*F
static constexpr int G3  = 4608;          // 3*HID
static constexpr int NB  = 128;           // GRU blocks
static constexpr int UPB = 12;            // hidden units per GRU block
static constexpr int RPB = 36;            // Whh rows per block (3 gates x 12)

// ---------- workspace layout (bytes) ----------
static constexpr size_t OFF_SEQ = 0;                           // bf16 [4096][6144]
static constexpr size_t OFF_WIH = 50331648;                    // bf16 [4608][6144]
static constexpr size_t OFF_GX  = OFF_WIH + 56623104;          // bf16 permuted [128*1000*144]
static constexpr size_t OFF_H   = OFF_GX + 37748736;           // u64 [2][2048] tagged h words

// =====================================================================
// Kernel 1: Wih fp32 -> bf16
// =====================================================================
__global__ __launch_bounds__(256) void cvt_wih_kernel(const float* __restrict__ W,
                                                      __bf16* __restrict__ Wb) {
    size_t i0 = ((size_t)blockIdx.x * 256 + threadIdx.x) * 4;
    size_t stride = (size_t)gridDim.x * 256 * 4;
    for (size_t i = i0; i < (size_t)G3 * INQ; i += stride) {
        float4 v = *(const float4*)(W + i);
        Wb[i + 0] = (__bf16)v.x;
        Wb[i + 1] = (__bf16)v.y;
        Wb[i + 2] = (__bf16)v.z;
        Wb[i + 3] = (__bf16)v.w;
    }
}

// =====================================================================
// Kernel 2: fused conv(q,k,v) + joint-softmax attention, one block per (b,t)
// =====================================================================
__global__ __launch_bounds__(256) void conv_attn_kernel(
    const float* __restrict__ x,
    const float* __restrict__ Wq, const float* __restrict__ bq,
    const float* __restrict__ Wk, const float* __restrict__ bk,
    const float* __restrict__ Wv, const float* __restrict__ bv,
    __bf16* __restrict__ seqB) {
    const int bt  = blockIdx.x;
    const int tid = threadIdx.x;
    __bf16* srow = seqB + (size_t)bt * INQ;
    if (bt >= BN * TN) {  // zero pad rows 4000..4095 (GEMM reads them)
        for (int i = tid; i < INQ; i += 256) srow[i] = (__bf16)0.f;
        return;
    }
    const int b = bt / TN, t = bt % TN;

    __shared__ union __attribute__((aligned(16))) {
        struct {
            __bf16 xcolT[96][64];   // [f][c*3+d], cols 48..63 zero
            __bf16 wls[64][64];     // [h][c*3+d], cols 48..63 zero (reloaded q/k/v)
        } c;
        __bf16 P[96][104];          // exp-weights [f][g] (overlays conv bufs)
    } u;
    __shared__ __attribute__((aligned(16))) __bf16 qT[96][72];   // [f][h]
    __shared__ __attribute__((aligned(16))) __bf16 kT[96][72];   // [g][h]
    __shared__ __attribute__((aligned(16))) __bf16 vhg[64][104]; // [h][g]
    __shared__ float red[8];

    const int lane = tid & 63, wv = tid >> 6;
    const int wm = wv >> 1, wn = wv & 1;
    const int n16 = lane & 15, quad = lane >> 4;

    // ---- build xcolT (im2col, freq-pad with 0) ----
    const float* xb = x + ((size_t)b * CN * TN + t) * FN;  // + c*TN*FN + f
    for (int idx = tid; idx < 96 * 64; idx += 256) {
        int f = idx >> 6, kk = idx & 63;
        float v = 0.f;
        if (kk < 48) {
            int c = kk / 3, d = kk % 3, fi = f + d - 1;
            if (fi >= 0 && fi < FN) v = xb[(size_t)c * TN * FN + fi];
        }
        u.c.xcolT[f][kk] = (__bf16)v;
    }

    auto load_w = [&](const float* W) {
        for (int idx = tid; idx < 64 * 64; idx += 256) {
            int h = idx >> 6, kk = idx & 63;
            u.c.wls[h][kk] = (__bf16)(kk < 48 ? W[h * 48 + kk] : 0.f);
        }
    };

    // conv producing transposed output [f][h] (for q and k)
    auto conv_T = [&](const float* bias, __bf16(*out)[72]) {
        f32x4 acc[3][2];
        for (int mt = 0; mt < 3; ++mt)
            for (int nt = 0; nt < 2; ++nt) acc[mt][nt] = f32x4{0.f, 0.f, 0.f, 0.f};
        #pragma unroll
        for (int ks = 0; ks < 2; ++ks) {
            bf16x8 a[3], bb[2];
            #pragma unroll
            for (int mt = 0; mt < 3; ++mt)
                a[mt] = *(const bf16x8*)&u.c.xcolT[(wm * 3 + mt) * 16 + n16][ks * 32 + quad * 8];
            #pragma unroll
            for (int nt = 0; nt < 2; ++nt)
                bb[nt] = *(const bf16x8*)&u.c.wls[(wn * 2 + nt) * 16 + n16][ks * 32 + quad * 8];
            #pragma unroll
            for (int mt = 0; mt < 3; ++mt)
                #pragma unroll
                for (int nt = 0; nt < 2; ++nt) acc[mt][nt] = MFMA16(a[mt], bb[nt], acc[mt][nt]);
        }
        #pragma unroll
        for (int mt = 0; mt < 3; ++mt)
            #pragma unroll
            for (int nt = 0; nt < 2; ++nt) {
                int h = (wn * 2 + nt) * 16 + n16;
                float bvv = bias[h];
                #pragma unroll
                for (int i = 0; i < 4; ++i) {
                    int f = (wm * 3 + mt) * 16 + quad * 4 + i;
                    out[f][h] = (__bf16)(acc[mt][nt][i] + bvv);
                }
            }
    };

    load_w(Wq);
    __syncthreads();
    conv_T(bq, qT);
    __syncthreads();
    load_w(Wk);
    __syncthreads();
    conv_T(bk, kT);
    __syncthreads();
    load_w(Wv);
    __syncthreads();
    {   // v: natural layout [h][f]
        f32x4 acc[2][3];
        for (int mt = 0; mt < 2; ++mt)
            for (int nt = 0; nt < 3; ++nt) acc[mt][nt] = f32x4{0.f, 0.f, 0.f, 0.f};
        #pragma unroll
        for (int ks = 0; ks < 2; ++ks) {
            bf16x8 a[2], bb[3];
            #pragma unroll
            for (int mt = 0; mt < 2; ++mt)
                a[mt] = *(const bf16x8*)&u.c.wls[(wm * 2 + mt) * 16 + n16][ks * 32 + quad * 8];
            #pragma unroll
            for (int nt = 0; nt < 3; ++nt)
                bb[nt] = *(const bf16x8*)&u.c.xcolT[(wn * 3 + nt) * 16 + n16][ks * 32 + quad * 8];
            #pragma unroll
            for (int mt = 0; mt < 2; ++mt)
                #pragma unroll
                for (int nt = 0; nt < 3; ++nt) acc[mt][nt] = MFMA16(a[mt], bb[nt], acc[mt][nt]);
        }
        #pragma unroll
        for (int mt = 0; mt < 2; ++mt)
            #pragma unroll
            for (int nt = 0; nt < 3; ++nt) {
                int f = (wn * 3 + nt) * 16 + n16;
                #pragma unroll
                for (int i = 0; i < 4; ++i) {
                    int h = (wm * 2 + mt) * 16 + quad * 4 + i;
                    vhg[h][f] = (__bf16)(acc[mt][nt][i] + bv[h]);
                }
            }
    }
    __syncthreads();

    // ---- S = qT*k / 8, joint softmax (keep S in registers) ----
    f32x4 sa[3][3];
    for (int mt = 0; mt < 3; ++mt)
        for (int nt = 0; nt < 3; ++nt) sa[mt][nt] = f32x4{0.f, 0.f, 0.f, 0.f};
    #pragma unroll
    for (int ks = 0; ks < 2; ++ks) {
        bf16x8 a[3], bb[3];
        #pragma unroll
        for (int mt = 0; mt < 3; ++mt)
            a[mt] = *(const bf16x8*)&qT[(wm * 3 + mt) * 16 + n16][ks * 32 + quad * 8];
        #pragma unroll
        for (int nt = 0; nt < 3; ++nt)
            bb[nt] = *(const bf16x8*)&kT[(wn * 3 + nt) * 16 + n16][ks * 32 + quad * 8];
        #pragma unroll
        for (int mt = 0; mt < 3; ++mt)
            #pragma unroll
            for (int nt = 0; nt < 3; ++nt) sa[mt][nt] = MFMA16(a[mt], bb[nt], sa[mt][nt]);
    }
    float mx = -1e30f;
    #pragma unroll
    for (int mt = 0; mt < 3; ++mt)
        #pragma unroll
        for (int nt = 0; nt < 3; ++nt)
            #pragma unroll
            for (int i = 0; i < 4; ++i) {
                float s = sa[mt][nt][i] * 0.125f;  // 1/sqrt(64)
                sa[mt][nt][i] = s;
                mx = fmaxf(mx, s);
            }
    #pragma unroll
    for (int m = 1; m < 64; m <<= 1) mx = fmaxf(mx, __shfl_xor(mx, m, 64));
    if (lane == 0) red[wv] = mx;
    __syncthreads();
    float M = fmaxf(fmaxf(red[0], red[1]), fmaxf(red[2], red[3]));
    float zs = 0.f;
    #pragma unroll
    for (int mt = 0; mt < 3; ++mt)
        #pragma unroll
        for (int nt = 0; nt < 3; ++nt) {
            int g = (wn * 3 + nt) * 16 + n16;
            #pragma unroll
            for (int i = 0; i < 4; ++i) {
                int f = (wm * 3 + mt) * 16 + quad * 4 + i;
                float e = __expf(sa[mt][nt][i] - M);
                zs += e;
                u.P[f][g] = (__bf16)e;
            }
        }
    #pragma unroll
    for (int m = 1; m < 64; m <<= 1) zs += __shfl_xor(zs, m, 64);
    if (lane == 0) red[4 + wv] = zs;
    __syncthreads();
    float zinv = 1.f / (red[4] + red[5] + red[6] + red[7]);

    // ---- PV: out[f][h] = sum_g P[f][g] * v[h][g] ----
    f32x4 pa[3][2];
    for (int mt = 0; mt < 3; ++mt)
        for (int nt = 0; nt < 2; ++nt) pa[mt][nt] = f32x4{0.f, 0.f, 0.f, 0.f};
    #pragma unroll
    for (int ks = 0; ks < 3; ++ks) {
        bf16x8 a[3], bb[2];
        #pragma unroll
        for (int mt = 0; mt < 3; ++mt)
            a[mt] = *(const bf16x8*)&u.P[(wm * 3 + mt) * 16 + n16][ks * 32 + quad * 8];
        #pragma unroll
        for (int nt = 0; nt < 2; ++nt)
            bb[nt] = *(const bf16x8*)&vhg[(wn * 2 + nt) * 16 + n16][ks * 32 + quad * 8];
        #pragma unroll
        for (int mt = 0; mt < 3; ++mt)
            #pragma unroll
            for (int nt = 0; nt < 2; ++nt) pa[mt][nt] = MFMA16(a[mt], bb[nt], pa[mt][nt]);
    }
    #pragma unroll
    for (int mt = 0; mt < 3; ++mt)
        #pragma unroll
        for (int nt = 0; nt < 2; ++nt) {
            int h = (wn * 2 + nt) * 16 + n16;
            #pragma unroll
            for (int i = 0; i < 4; ++i) {
                int f = (wm * 3 + mt) * 16 + quad * 4 + i;
                srow[f * 64 + h] = (__bf16)(pa[mt][nt][i] * zinv);
            }
        }
}

// =====================================================================
// Kernel 3: gx = seq @ Wih^T + bih, written GRU-block-permuted:
// gxp[(ublk*1000 + t)*144 + gb*36 + gate*12 + ju]  (ublk=u/12, ju=u%12)
// =====================================================================
__global__ __launch_bounds__(256) void gemm_kernel(const __bf16* __restrict__ A,
                                                   const __bf16* __restrict__ Bw,
                                                   const float* __restrict__ bih,
                                                   __bf16* __restrict__ gxp) {
    const int bn = blockIdx.x;  // 36 N-tiles
    const int bm = blockIdx.y;  // 32 M-tiles
    const int tid = threadIdx.x;
    __shared__ __attribute__((aligned(16))) __bf16 As[128 * 64];
    __shared__ __attribute__((aligned(16))) __bf16 Bs[128 * 64];
    const int lane = tid & 63, wv = tid >> 6, wm = wv >> 1, wn = wv & 1;
    const int n16 = lane & 15, quad = lane >> 4;

    const int r  = tid >> 3;         // staging row 0..31
    const int c8 = (tid & 7) * 8;    // staging col (elems)
    const __bf16* ag = A  + ((size_t)(bm * 128 + r)) * INQ + c8;
    const __bf16* bg = Bw + ((size_t)(bn * 128 + r)) * INQ + c8;
    __bf16* as_dst = As + r * 64 + c8;
    __bf16* bs_dst = Bs + r * 64 + c8;

    f32x4 acc[4][4];
    for (int mt = 0; mt < 4; ++mt)
        for (int nt = 0; nt < 4; ++nt) acc[mt][nt] = f32x4{0.f, 0.f, 0.f, 0.f};

    for (int kt = 0; kt < 96; ++kt) {
        #pragma unroll
        for (int i = 0; i < 4; ++i) {
            ASYNC_CP16(ag + (size_t)i * 32 * INQ, as_dst + i * 32 * 64);
            ASYNC_CP16(bg + (size_t)i * 32 * INQ, bs_dst + i * 32 * 64);
        }
        ag += 64;
        bg += 64;
        __syncthreads();
        #pragma unroll
        for (int kk = 0; kk < 2; ++kk) {
            bf16x8 af[4], bf[4];
            #pragma unroll
            for (int mt = 0; mt < 4; ++mt)
                af[mt] = *(const bf16x8*)&As[(wm * 64 + mt * 16 + n16) * 64 + kk * 32 + quad * 8];
            #pragma unroll
            for (int nt = 0; nt < 4; ++nt)
                bf[nt] = *(const bf16x8*)&Bs[(wn * 64 + nt * 16 + n16) * 64 + kk * 32 + quad * 8];
            #pragma unroll
            for (int mt = 0; mt < 4; ++mt)
                #pragma unroll
                for (int nt = 0; nt < 4; ++nt) acc[mt][nt] = MFMA16(af[mt], bf[nt], acc[mt][nt]);
        }
        __syncthreads();
    }
    #pragma unroll
    for (int nt = 0; nt < 4; ++nt) {
        int n = bn * 128 + wn * 64 + nt * 16 + n16;
        float bvv = bih[n];
        int gate = n / HID;
        int uu = n - gate * HID;
        int ublk = uu / UPB, ju = uu - ublk * UPB;
        #pragma unroll
        for (int mt = 0; mt < 4; ++mt) {
            int m0 = bm * 128 + wm * 64 + mt * 16 + quad * 4;
            #pragma unroll
            for (int i = 0; i < 4; ++i) {
                int m = m0 + i;
                if (m < BN * TN) {
                    int gb = m / TN, tt = m - gb * TN;
                    gxp[((size_t)ublk * TN + tt) * 144 + gb * 36 + gate * 12 + ju] =
                        (__bf16)(acc[mt][nt][i] + bvv);
                }
            }
        }
    }
}

// =====================================================================
// Kernel 4: persistent GRU scan, BARRIER-FREE tagged-data polling.
// h word = u64: 3 bf16 units (bits 0..47) + step tag (bits 48..63).
// h[t] lives in slot t&1 with tag t+1; consumers poll their own 8 words,
// detection == data delivery. Safety: a block stores tag t+2 only after
// seeing all tags t+1, proving every block finished reading h[t-1]'s slot.
// 128 blocks x 12 units; Whh slice (36 rows, 112 KB bf16) in LDS.
// =====================================================================
__global__ __launch_bounds__(256) void gru_kernel(const __bf16* __restrict__ gxp,
                                                  const float* __restrict__ Whh,
                                                  const float* __restrict__ bhh,
                                                  const float* __restrict__ h0,
                                                  u64* __restrict__ hbuf,
                                                  float* __restrict__ out) {
    const int blk = blockIdx.x;   // 128
    const int tid = threadIdx.x;
    const int u0 = blk * UPB;
    constexpr int LDW = 1560;     // padded row stride (elems)
    __shared__ __attribute__((aligned(16))) __bf16 Wl[RPB][LDW]; // rows: gate*12+ju
    __shared__ __attribute__((aligned(16))) __bf16 hl[4][LDW];   // [batch][k]
    __shared__ float part[4][4][48];                             // [wave][batch][row]
    __shared__ unsigned short hpack[4][12];                      // [batch][ju] bf16 bits

    const int lane = tid & 63, wvi = tid >> 6;
    const int n16 = lane & 15, quad = lane >> 4;

    // load Whh slice (fp32 -> bf16), once
    for (int idx = tid; idx < RPB * HID; idx += 256) {
        int j = idx / HID, cc = idx - j * HID;   // j = gate*12 + ju
        int g = j / 12, ju = j - g * 12;
        Wl[j][cc] = (__bf16)Whh[(size_t)(g * HID + u0 + ju) * HID + cc];
    }

    // gate-thread setup (tid < 48): gb = batch, ju = unit offset
    const int gb = tid / 12, ju = tid - gb * 12;
    float hreg = 0.f, bhr = 0.f, bhz = 0.f, bhn = 0.f;
    float xr = 0.f, xz = 0.f, xn = 0.f;
    const __bf16* gxme = gxp + (size_t)blk * TN * 144 + gb * 36 + ju;
    if (tid < 48) {
        hreg = h0[gb * HID + u0 + ju];
        bhr = bhh[u0 + ju];
        bhz = bhh[HID + u0 + ju];
        bhn = bhh[2 * HID + u0 + ju];
        xr = (float)gxme[0];      // t = 0 prefetch
        xz = (float)gxme[12];
        xn = (float)gxme[24];
    }
    // publish h[0] (slot 0, tag 1): 16 threads pack 3 units each from h0
    if (tid < 16) {
        int b0 = tid >> 2, q = tid & 3;
        const float* hp = h0 + b0 * HID + u0 + q * 3;
        union { __bf16 h; unsigned short s; } c0, c1, c2;
        c0.h = (__bf16)hp[0]; c1.h = (__bf16)hp[1]; c2.h = (__bf16)hp[2];
        u64 p = (u64)c0.s | ((u64)c1.s << 16) | ((u64)c2.s << 32) | ((u64)1 << 48);
        __hip_atomic_store(hbuf + b0 * 512 + blk * 4 + q, p,
                           __ATOMIC_RELAXED, __HIP_MEMORY_SCOPE_AGENT);
    }
    __syncthreads();   // Wl ready

    for (int t = 0; t < TN; ++t) {
        // ---- poll own 8 tagged words of h[t] (slot t&1, tag t+1) ----
        const u64* hs = hbuf + (size_t)(t & 1) * 2048 + tid * 8;
        const unsigned short want = (unsigned short)(t + 1);
        u64 w[8];
        unsigned need = 0xffu;
        do {
            #pragma unroll
            for (int k = 0; k < 8; ++k)
                if (need & (1u << k))
                    w[k] = __hip_atomic_load(hs + k, __ATOMIC_RELAXED,
                                             __HIP_MEMORY_SCOPE_AGENT);
            #pragma unroll
            for (int k = 0; k < 8; ++k)
                if ((unsigned short)(w[k] >> 48) == want) need &= ~(1u << k);
        } while (need);

        // ---- unpack 8 words -> 24 contiguous bf16 in hl[batch] ----
        {
            union { unsigned short s[24]; bf16x8 v[3]; } up;
            #pragma unroll
            for (int k = 0; k < 8; ++k) {
                up.s[3 * k]     = (unsigned short)w[k];
                up.s[3 * k + 1] = (unsigned short)(w[k] >> 16);
                up.s[3 * k + 2] = (unsigned short)(w[k] >> 32);
            }
            __bf16* dst = &hl[wvi][(tid & 63) * 24];   // batch = wvi, units contiguous
            *(bf16x8*)(dst)      = up.v[0];
            *(bf16x8*)(dst + 8)  = up.v[1];
            *(bf16x8*)(dst + 16) = up.v[2];
        }
        __syncthreads();

        // ---- matvec: D[batch][row] += h . Whh, K split over 4 waves ----
        const int kbase = wvi * 384;
        f32x4 a0[3], a1[3];
        #pragma unroll
        for (int nt = 0; nt < 3; ++nt) {
            a0[nt] = f32x4{0.f, 0.f, 0.f, 0.f};
            a1[nt] = f32x4{0.f, 0.f, 0.f, 0.f};
        }
        const int hr = n16 & 3;
        int wrow[3];
        #pragma unroll
        for (int nt = 0; nt < 3; ++nt) {
            int rr = nt * 16 + n16;
            wrow[nt] = (rr < RPB) ? rr : 0;
        }
        #pragma unroll
        for (int ks = 0; ks < 12; ++ks) {
            int k = kbase + ks * 32 + quad * 8;
            bf16x8 av = *(const bf16x8*)&hl[hr][k];
            #pragma unroll
            for (int nt = 0; nt < 3; ++nt) {
                bf16x8 bv = *(const bf16x8*)&Wl[wrow[nt]][k];
                if (ks & 1) a1[nt] = MFMA16(av, bv, a1[nt]);
                else        a0[nt] = MFMA16(av, bv, a0[nt]);
            }
        }
        if (quad == 0) {
            #pragma unroll
            for (int nt = 0; nt < 3; ++nt) {
                if (nt * 16 + n16 < RPB) {
                    f32x4 acc = a0[nt] + a1[nt];
                    #pragma unroll
                    for (int i = 0; i < 4; ++i) part[wvi][i][nt * 16 + n16] = acc[i];
                }
            }
        }
        __syncthreads();

        // ---- gates (48 threads, all wave 0) ----
        if (tid < 48) {
            float gr = 0.f, gz = 0.f, gn = 0.f;
            #pragma unroll
            for (int w4 = 0; w4 < 4; ++w4) {
                gr += part[w4][gb][ju];
                gz += part[w4][gb][12 + ju];
                gn += part[w4][gb][24 + ju];
            }
            float rr = 1.f / (1.f + __expf(-(xr + gr + bhr)));
            float zz = 1.f / (1.f + __expf(-(xz + gz + bhz)));
            float nn = tanhf(xn + rr * (gn + bhn));
            float hn = (1.f - zz) * nn + zz * hreg;
            hreg = hn;
            union { __bf16 h; unsigned short s; } cv;
            cv.h = (__bf16)hn;
            hpack[gb][ju] = cv.s;          // same-wave LDS exchange
            int uu = u0 + ju;
            out[((size_t)(gb * CN + uu / FN) * TN + t) * FN + (uu % FN)] = hn;
            if (ju % 3 == 0) {             // pack 3 units + tag, one u64 store
                int q = ju / 3;
                u64 p = (u64)hpack[gb][ju] | ((u64)hpack[gb][ju + 1] << 16) |
                        ((u64)hpack[gb][ju + 2] << 32) |
                        ((u64)(unsigned short)(t + 2) << 48);
                __hip_atomic_store(hbuf + (size_t)((t + 1) & 1) * 2048 + gb * 512 + blk * 4 + q,
                                   p, __ATOMIC_RELAXED, __HIP_MEMORY_SCOPE_AGENT);
            }
            // prefetch gx for step t+1 (off critical path)
            const __bf16* gnx = gxme + (size_t)(t + 1) * 144;
            xr = (float)gnx[0];
            xz = (float)gnx[12];
            xn = (float)gnx[24];
        }
        // no barrier: next poll self-synchronizes; hl overwrite is safe because
        // passing the poll implies every block (incl. ours) finished this step.
    }
    if (tid < 48) out[(size_t)BN * CN * TN * FN + gb * HID + u0 + ju] = hreg;
}

// =====================================================================
extern "C" void kernel_launch(void* const* d_in, const int* in_sizes, int n_in,
                              void* d_out, int out_size, void* d_ws, size_t ws_size,
                              hipStream_t stream) {
    const float* x   = (const float*)d_in[0];
    const float* h0  = (const float*)d_in[1];
    const float* Wq  = (const float*)d_in[2];
    const float* bq  = (const float*)d_in[3];
    const float* Wk  = (const float*)d_in[4];
    const float* bk  = (const float*)d_in[5];
    const float* Wv  = (const float*)d_in[6];
    const float* bv  = (const float*)d_in[7];
    const float* Wih = (const float*)d_in[8];
    const float* Whh = (const float*)d_in[9];
    const float* bih = (const float*)d_in[10];
    const float* bhh = (const float*)d_in[11];
    float* out = (float*)d_out;
    char* ws = (char*)d_ws;
    __bf16* seqB = (__bf16*)(ws + OFF_SEQ);
    __bf16* WihB = (__bf16*)(ws + OFF_WIH);
    __bf16* gxB  = (__bf16*)(ws + OFF_GX);
    u64*    hbuf = (u64*)(ws + OFF_H);

    hipLaunchKernelGGL(cvt_wih_kernel, dim3(2048), dim3(256), 0, stream, Wih, WihB);
    hipLaunchKernelGGL(conv_attn_kernel, dim3(4096), dim3(256), 0, stream,
                       x, Wq, bq, Wk, bk, Wv, bv, seqB);
    hipLaunchKernelGGL(gemm_kernel, dim3(36, 32), dim3(256), 0, stream, seqB, WihB, bih, gxB);

    void* args[] = {(void*)&gxB, (void*)&Whh, (void*)&bhh, (void*)&h0,
                    (void*)&hbuf, (void*)&out};
    hipLaunchCooperativeKernel((void*)gru_kernel, dim3(NB), dim3(256), args, 0, stream);
}

// Round 7
// 5023.504 us; speedup vs baseline: 1.1132x; 1.1132x over previous
//
#include <hip/hip_runtime.h>
#include <hip/hip_bf16.h>
#include <cstdint>
#include <cstddef>

// ---------- types ----------
typedef __bf16 bf16x8 __attribute__((ext_vector_type(8)));
typedef float  f32x4  __attribute__((ext_vector_type(4)));
typedef unsigned long long u64;

#define MFMA16(a, b, c) __builtin_amdgcn_mfma_f32_16x16x32_bf16((a), (b), (c), 0, 0, 0)

// async global->LDS, 16B per lane (wave-uniform base + lane*16 layout honored below)
#define ASYNC_CP16(gsrc, ldst)                                                              \
    __builtin_amdgcn_global_load_lds((const __attribute__((address_space(1))) void*)(gsrc), \
                                     (__attribute__((address_space(3))) void*)(ldst), 16, 0, 0)

// ---------- problem constants ----------
static constexpr int BN = 4, CN = 16, TN = 1000, FN = 96, HN = 64;
static constexpr int HID = 1536;          // C*F
static constexpr int INQ = 6144;          // H*F
static constexpr int G3  = 4608;          // 3*HID
static constexpr int NB  = 128;           // GRU blocks
static constexpr int UPB = 12;            // hidden units per GRU block
static constexpr int RPB = 36;            // Whh rows per block (3 gates x 12)

// ---------- workspace layout (bytes) ----------
static constexpr size_t OFF_SEQ = 0;                           // bf16 [4096][6144]
static constexpr size_t OFF_WIH = 50331648;                    // bf16 [4608][6144]
static constexpr size_t OFF_GX  = OFF_WIH + 56623104;          // bf16 permuted [128*1000*144]
static constexpr size_t OFF_H   = OFF_GX + 37748736;           // u64 [2][2048] tagged h words

// =====================================================================
// Kernel 1: Wih fp32 -> bf16
// =====================================================================
__global__ __launch_bounds__(256) void cvt_wih_kernel(const float* __restrict__ W,
                                                      __bf16* __restrict__ Wb) {
    size_t i0 = ((size_t)blockIdx.x * 256 + threadIdx.x) * 4;
    size_t stride = (size_t)gridDim.x * 256 * 4;
    for (size_t i = i0; i < (size_t)G3 * INQ; i += stride) {
        float4 v = *(const float4*)(W + i);
        Wb[i + 0] = (__bf16)v.x;
        Wb[i + 1] = (__bf16)v.y;
        Wb[i + 2] = (__bf16)v.z;
        Wb[i + 3] = (__bf16)v.w;
    }
}

// =====================================================================
// Kernel 2: fused conv(q,k,v) + joint-softmax attention, one block per (b,t)
// =====================================================================
__global__ __launch_bounds__(256) void conv_attn_kernel(
    const float* __restrict__ x,
    const float* __restrict__ Wq, const float* __restrict__ bq,
    const float* __restrict__ Wk, const float* __restrict__ bk,
    const float* __restrict__ Wv, const float* __restrict__ bv,
    __bf16* __restrict__ seqB) {
    const int bt  = blockIdx.x;
    const int tid = threadIdx.x;
    __bf16* srow = seqB + (size_t)bt * INQ;
    if (bt >= BN * TN) {  // zero pad rows 4000..4095 (GEMM reads them)
        for (int i = tid; i < INQ; i += 256) srow[i] = (__bf16)0.f;
        return;
    }
    const int b = bt / TN, t = bt % TN;

    __shared__ union __attribute__((aligned(16))) {
        struct {
            __bf16 xcolT[96][64];   // [f][c*3+d], cols 48..63 zero
            __bf16 wls[64][64];     // [h][c*3+d], cols 48..63 zero (reloaded q/k/v)
        } c;
        __bf16 P[96][104];          // exp-weights [f][g] (overlays conv bufs)
    } u;
    __shared__ __attribute__((aligned(16))) __bf16 qT[96][72];   // [f][h]
    __shared__ __attribute__((aligned(16))) __bf16 kT[96][72];   // [g][h]
    __shared__ __attribute__((aligned(16))) __bf16 vhg[64][104]; // [h][g]
    __shared__ float red[8];

    const int lane = tid & 63, wv = tid >> 6;
    const int wm = wv >> 1, wn = wv & 1;
    const int n16 = lane & 15, quad = lane >> 4;

    // ---- build xcolT (im2col, freq-pad with 0) ----
    const float* xb = x + ((size_t)b * CN * TN + t) * FN;  // + c*TN*FN + f
    for (int idx = tid; idx < 96 * 64; idx += 256) {
        int f = idx >> 6, kk = idx & 63;
        float v = 0.f;
        if (kk < 48) {
            int c = kk / 3, d = kk % 3, fi = f + d - 1;
            if (fi >= 0 && fi < FN) v = xb[(size_t)c * TN * FN + fi];
        }
        u.c.xcolT[f][kk] = (__bf16)v;
    }

    auto load_w = [&](const float* W) {
        for (int idx = tid; idx < 64 * 64; idx += 256) {
            int h = idx >> 6, kk = idx & 63;
            u.c.wls[h][kk] = (__bf16)(kk < 48 ? W[h * 48 + kk] : 0.f);
        }
    };

    // conv producing transposed output [f][h] (for q and k)
    auto conv_T = [&](const float* bias, __bf16(*out)[72]) {
        f32x4 acc[3][2];
        for (int mt = 0; mt < 3; ++mt)
            for (int nt = 0; nt < 2; ++nt) acc[mt][nt] = f32x4{0.f, 0.f, 0.f, 0.f};
        #pragma unroll
        for (int ks = 0; ks < 2; ++ks) {
            bf16x8 a[3], bb[2];
            #pragma unroll
            for (int mt = 0; mt < 3; ++mt)
                a[mt] = *(const bf16x8*)&u.c.xcolT[(wm * 3 + mt) * 16 + n16][ks * 32 + quad * 8];
            #pragma unroll
            for (int nt = 0; nt < 2; ++nt)
                bb[nt] = *(const bf16x8*)&u.c.wls[(wn * 2 + nt) * 16 + n16][ks * 32 + quad * 8];
            #pragma unroll
            for (int mt = 0; mt < 3; ++mt)
                #pragma unroll
                for (int nt = 0; nt < 2; ++nt) acc[mt][nt] = MFMA16(a[mt], bb[nt], acc[mt][nt]);
        }
        #pragma unroll
        for (int mt = 0; mt < 3; ++mt)
            #pragma unroll
            for (int nt = 0; nt < 2; ++nt) {
                int h = (wn * 2 + nt) * 16 + n16;
                float bvv = bias[h];
                #pragma unroll
                for (int i = 0; i < 4; ++i) {
                    int f = (wm * 3 + mt) * 16 + quad * 4 + i;
                    out[f][h] = (__bf16)(acc[mt][nt][i] + bvv);
                }
            }
    };

    load_w(Wq);
    __syncthreads();
    conv_T(bq, qT);
    __syncthreads();
    load_w(Wk);
    __syncthreads();
    conv_T(bk, kT);
    __syncthreads();
    load_w(Wv);
    __syncthreads();
    {   // v: natural layout [h][f]
        f32x4 acc[2][3];
        for (int mt = 0; mt < 2; ++mt)
            for (int nt = 0; nt < 3; ++nt) acc[mt][nt] = f32x4{0.f, 0.f, 0.f, 0.f};
        #pragma unroll
        for (int ks = 0; ks < 2; ++ks) {
            bf16x8 a[2], bb[3];
            #pragma unroll
            for (int mt = 0; mt < 2; ++mt)
                a[mt] = *(const bf16x8*)&u.c.wls[(wm * 2 + mt) * 16 + n16][ks * 32 + quad * 8];
            #pragma unroll
            for (int nt = 0; nt < 3; ++nt)
                bb[nt] = *(const bf16x8*)&u.c.xcolT[(wn * 3 + nt) * 16 + n16][ks * 32 + quad * 8];
            #pragma unroll
            for (int mt = 0; mt < 2; ++mt)
                #pragma unroll
                for (int nt = 0; nt < 3; ++nt) acc[mt][nt] = MFMA16(a[mt], bb[nt], acc[mt][nt]);
        }
        #pragma unroll
        for (int mt = 0; mt < 2; ++mt)
            #pragma unroll
            for (int nt = 0; nt < 3; ++nt) {
                int f = (wn * 3 + nt) * 16 + n16;
                #pragma unroll
                for (int i = 0; i < 4; ++i) {
                    int h = (wm * 2 + mt) * 16 + quad * 4 + i;
                    vhg[h][f] = (__bf16)(acc[mt][nt][i] + bv[h]);
                }
            }
    }
    __syncthreads();

    // ---- S = qT*k / 8, joint softmax (keep S in registers) ----
    f32x4 sa[3][3];
    for (int mt = 0; mt < 3; ++mt)
        for (int nt = 0; nt < 3; ++nt) sa[mt][nt] = f32x4{0.f, 0.f, 0.f, 0.f};
    #pragma unroll
    for (int ks = 0; ks < 2; ++ks) {
        bf16x8 a[3], bb[3];
        #pragma unroll
        for (int mt = 0; mt < 3; ++mt)
            a[mt] = *(const bf16x8*)&qT[(wm * 3 + mt) * 16 + n16][ks * 32 + quad * 8];
        #pragma unroll
        for (int nt = 0; nt < 3; ++nt)
            bb[nt] = *(const bf16x8*)&kT[(wn * 3 + nt) * 16 + n16][ks * 32 + quad * 8];
        #pragma unroll
        for (int mt = 0; mt < 3; ++mt)
            #pragma unroll
            for (int nt = 0; nt < 3; ++nt) sa[mt][nt] = MFMA16(a[mt], bb[nt], sa[mt][nt]);
    }
    float mx = -1e30f;
    #pragma unroll
    for (int mt = 0; mt < 3; ++mt)
        #pragma unroll
        for (int nt = 0; nt < 3; ++nt)
            #pragma unroll
            for (int i = 0; i < 4; ++i) {
                float s = sa[mt][nt][i] * 0.125f;  // 1/sqrt(64)
                sa[mt][nt][i] = s;
                mx = fmaxf(mx, s);
            }
    #pragma unroll
    for (int m = 1; m < 64; m <<= 1) mx = fmaxf(mx, __shfl_xor(mx, m, 64));
    if (lane == 0) red[wv] = mx;
    __syncthreads();
    float M = fmaxf(fmaxf(red[0], red[1]), fmaxf(red[2], red[3]));
    float zs = 0.f;
    #pragma unroll
    for (int mt = 0; mt < 3; ++mt)
        #pragma unroll
        for (int nt = 0; nt < 3; ++nt) {
            int g = (wn * 3 + nt) * 16 + n16;
            #pragma unroll
            for (int i = 0; i < 4; ++i) {
                int f = (wm * 3 + mt) * 16 + quad * 4 + i;
                float e = __expf(sa[mt][nt][i] - M);
                zs += e;
                u.P[f][g] = (__bf16)e;
            }
        }
    #pragma unroll
    for (int m = 1; m < 64; m <<= 1) zs += __shfl_xor(zs, m, 64);
    if (lane == 0) red[4 + wv] = zs;
    __syncthreads();
    float zinv = 1.f / (red[4] + red[5] + red[6] + red[7]);

    // ---- PV: out[f][h] = sum_g P[f][g] * v[h][g] ----
    f32x4 pa[3][2];
    for (int mt = 0; mt < 3; ++mt)
        for (int nt = 0; nt < 2; ++nt) pa[mt][nt] = f32x4{0.f, 0.f, 0.f, 0.f};
    #pragma unroll
    for (int ks = 0; ks < 3; ++ks) {
        bf16x8 a[3], bb[2];
        #pragma unroll
        for (int mt = 0; mt < 3; ++mt)
            a[mt] = *(const bf16x8*)&u.P[(wm * 3 + mt) * 16 + n16][ks * 32 + quad * 8];
        #pragma unroll
        for (int nt = 0; nt < 2; ++nt)
            bb[nt] = *(const bf16x8*)&vhg[(wn * 2 + nt) * 16 + n16][ks * 32 + quad * 8];
        #pragma unroll
        for (int mt = 0; mt < 3; ++mt)
            #pragma unroll
            for (int nt = 0; nt < 2; ++nt) pa[mt][nt] = MFMA16(a[mt], bb[nt], pa[mt][nt]);
    }
    #pragma unroll
    for (int mt = 0; mt < 3; ++mt)
        #pragma unroll
        for (int nt = 0; nt < 2; ++nt) {
            int h = (wn * 2 + nt) * 16 + n16;
            #pragma unroll
            for (int i = 0; i < 4; ++i) {
                int f = (wm * 3 + mt) * 16 + quad * 4 + i;
                srow[f * 64 + h] = (__bf16)(pa[mt][nt][i] * zinv);
            }
        }
}

// =====================================================================
// Kernel 3: gx = seq @ Wih^T + bih, written GRU-block-permuted:
// gxp[(ublk*1000 + t)*144 + gb*36 + gate*12 + ju]  (ublk=u/12, ju=u%12)
// =====================================================================
__global__ __launch_bounds__(256) void gemm_kernel(const __bf16* __restrict__ A,
                                                   const __bf16* __restrict__ Bw,
                                                   const float* __restrict__ bih,
                                                   __bf16* __restrict__ gxp) {
    const int bn = blockIdx.x;  // 36 N-tiles
    const int bm = blockIdx.y;  // 32 M-tiles
    const int tid = threadIdx.x;
    __shared__ __attribute__((aligned(16))) __bf16 As[128 * 64];
    __shared__ __attribute__((aligned(16))) __bf16 Bs[128 * 64];
    const int lane = tid & 63, wv = tid >> 6, wm = wv >> 1, wn = wv & 1;
    const int n16 = lane & 15, quad = lane >> 4;

    const int r  = tid >> 3;         // staging row 0..31
    const int c8 = (tid & 7) * 8;    // staging col (elems)
    const __bf16* ag = A  + ((size_t)(bm * 128 + r)) * INQ + c8;
    const __bf16* bg = Bw + ((size_t)(bn * 128 + r)) * INQ + c8;
    __bf16* as_dst = As + r * 64 + c8;
    __bf16* bs_dst = Bs + r * 64 + c8;

    f32x4 acc[4][4];
    for (int mt = 0; mt < 4; ++mt)
        for (int nt = 0; nt < 4; ++nt) acc[mt][nt] = f32x4{0.f, 0.f, 0.f, 0.f};

    for (int kt = 0; kt < 96; ++kt) {
        #pragma unroll
        for (int i = 0; i < 4; ++i) {
            ASYNC_CP16(ag + (size_t)i * 32 * INQ, as_dst + i * 32 * 64);
            ASYNC_CP16(bg + (size_t)i * 32 * INQ, bs_dst + i * 32 * 64);
        }
        ag += 64;
        bg += 64;
        __syncthreads();
        #pragma unroll
        for (int kk = 0; kk < 2; ++kk) {
            bf16x8 af[4], bf[4];
            #pragma unroll
            for (int mt = 0; mt < 4; ++mt)
                af[mt] = *(const bf16x8*)&As[(wm * 64 + mt * 16 + n16) * 64 + kk * 32 + quad * 8];
            #pragma unroll
            for (int nt = 0; nt < 4; ++nt)
                bf[nt] = *(const bf16x8*)&Bs[(wn * 64 + nt * 16 + n16) * 64 + kk * 32 + quad * 8];
            #pragma unroll
            for (int mt = 0; mt < 4; ++mt)
                #pragma unroll
                for (int nt = 0; nt < 4; ++nt) acc[mt][nt] = MFMA16(af[mt], bf[nt], acc[mt][nt]);
        }
        __syncthreads();
    }
    #pragma unroll
    for (int nt = 0; nt < 4; ++nt) {
        int n = bn * 128 + wn * 64 + nt * 16 + n16;
        float bvv = bih[n];
        int gate = n / HID;
        int uu = n - gate * HID;
        int ublk = uu / UPB, ju = uu - ublk * UPB;
        #pragma unroll
        for (int mt = 0; mt < 4; ++mt) {
            int m0 = bm * 128 + wm * 64 + mt * 16 + quad * 4;
            #pragma unroll
            for (int i = 0; i < 4; ++i) {
                int m = m0 + i;
                if (m < BN * TN) {
                    int gb = m / TN, tt = m - gb * TN;
                    gxp[((size_t)ublk * TN + tt) * 144 + gb * 36 + gate * 12 + ju] =
                        (__bf16)(acc[mt][nt][i] + bvv);
                }
            }
        }
    }
}

// =====================================================================
// Kernel 4: persistent GRU scan, BARRIER-FREE tagged-data polling.
// h word = u64: 3 bf16 units (bits 0..47) + step tag (bits 48..63).
// Poll loop is UNCONDITIONAL-BATCHED: all 8 loads issue back-to-back each
// sweep (no divergent masked reload), so sweep period ~= one LLC latency
// instead of 8x. Detection == data delivery. Safety: a block stores tag
// t+2 only after seeing all tags t+1 (slots double-buffered by t&1).
// 128 blocks x 12 units; Whh slice (36 rows, 112 KB bf16) in LDS.
// =====================================================================
__global__ __launch_bounds__(256) void gru_kernel(const __bf16* __restrict__ gxp,
                                                  const float* __restrict__ Whh,
                                                  const float* __restrict__ bhh,
                                                  const float* __restrict__ h0,
                                                  u64* __restrict__ hbuf,
                                                  float* __restrict__ out) {
    const int blk = blockIdx.x;   // 128
    const int tid = threadIdx.x;
    const int u0 = blk * UPB;
    constexpr int LDW = 1560;     // padded row stride (elems)
    __shared__ __attribute__((aligned(16))) __bf16 Wl[RPB][LDW]; // rows: gate*12+ju
    __shared__ __attribute__((aligned(16))) __bf16 hl[4][LDW];   // [batch][k]
    __shared__ float part[4][4][48];                             // [wave][batch][row]
    __shared__ unsigned short hpack[4][12];                      // [batch][ju] bf16 bits

    const int lane = tid & 63, wvi = tid >> 6;
    const int n16 = lane & 15, quad = lane >> 4;

    // load Whh slice (fp32 -> bf16), once
    for (int idx = tid; idx < RPB * HID; idx += 256) {
        int j = idx / HID, cc = idx - j * HID;   // j = gate*12 + ju
        int g = j / 12, ju = j - g * 12;
        Wl[j][cc] = (__bf16)Whh[(size_t)(g * HID + u0 + ju) * HID + cc];
    }

    // gate-thread setup (tid < 48): gb = batch, ju = unit offset
    const int gb = tid / 12, ju = tid - gb * 12;
    float hreg = 0.f, bhr = 0.f, bhz = 0.f, bhn = 0.f;
    float xr = 0.f, xz = 0.f, xn = 0.f;
    const __bf16* gxme = gxp + (size_t)blk * TN * 144 + gb * 36 + ju;
    if (tid < 48) {
        hreg = h0[gb * HID + u0 + ju];
        bhr = bhh[u0 + ju];
        bhz = bhh[HID + u0 + ju];
        bhn = bhh[2 * HID + u0 + ju];
        xr = (float)gxme[0];      // t = 0 prefetch
        xz = (float)gxme[12];
        xn = (float)gxme[24];
    }
    // publish h[0] (slot 0, tag 1): 16 threads pack 3 units each from h0
    if (tid < 16) {
        int b0 = tid >> 2, q = tid & 3;
        const float* hp = h0 + b0 * HID + u0 + q * 3;
        union { __bf16 h; unsigned short s; } c0, c1, c2;
        c0.h = (__bf16)hp[0]; c1.h = (__bf16)hp[1]; c2.h = (__bf16)hp[2];
        u64 p = (u64)c0.s | ((u64)c1.s << 16) | ((u64)c2.s << 32) | ((u64)1 << 48);
        __hip_atomic_store(hbuf + b0 * 512 + blk * 4 + q, p,
                           __ATOMIC_RELAXED, __HIP_MEMORY_SCOPE_AGENT);
    }
    __syncthreads();   // Wl ready

    for (int t = 0; t < TN; ++t) {
        // ---- poll own 8 tagged words of h[t] (slot t&1, tag t+1) ----
        // UNCONDITIONAL batched sweep: 8 independent loads, then checks.
        const u64* hs = hbuf + (size_t)(t & 1) * 2048 + tid * 8;
        const unsigned short want = (unsigned short)(t + 1);
        u64 w[8];
        for (;;) {
            #pragma unroll
            for (int k = 0; k < 8; ++k)
                w[k] = __hip_atomic_load(hs + k, __ATOMIC_RELAXED,
                                         __HIP_MEMORY_SCOPE_AGENT);
            unsigned ok = 1u;
            #pragma unroll
            for (int k = 0; k < 8; ++k)
                ok &= (unsigned)((unsigned short)(w[k] >> 48) == want);
            if (ok) break;
        }

        // ---- unpack 8 words -> 24 contiguous bf16 in hl[batch] ----
        {
            union { unsigned short s[24]; bf16x8 v[3]; } up;
            #pragma unroll
            for (int k = 0; k < 8; ++k) {
                up.s[3 * k]     = (unsigned short)w[k];
                up.s[3 * k + 1] = (unsigned short)(w[k] >> 16);
                up.s[3 * k + 2] = (unsigned short)(w[k] >> 32);
            }
            __bf16* dst = &hl[wvi][(tid & 63) * 24];   // batch = wvi, units contiguous
            *(bf16x8*)(dst)      = up.v[0];
            *(bf16x8*)(dst + 8)  = up.v[1];
            *(bf16x8*)(dst + 16) = up.v[2];
        }
        __syncthreads();

        // ---- matvec: D[batch][row] += h . Whh, K split over 4 waves ----
        const int kbase = wvi * 384;
        f32x4 a0[3], a1[3];
        #pragma unroll
        for (int nt = 0; nt < 3; ++nt) {
            a0[nt] = f32x4{0.f, 0.f, 0.f, 0.f};
            a1[nt] = f32x4{0.f, 0.f, 0.f, 0.f};
        }
        const int hr = n16 & 3;
        int wrow[3];
        #pragma unroll
        for (int nt = 0; nt < 3; ++nt) {
            int rr = nt * 16 + n16;
            wrow[nt] = (rr < RPB) ? rr : 0;
        }
        #pragma unroll
        for (int ks = 0; ks < 12; ++ks) {
            int k = kbase + ks * 32 + quad * 8;
            bf16x8 av = *(const bf16x8*)&hl[hr][k];
            #pragma unroll
            for (int nt = 0; nt < 3; ++nt) {
                bf16x8 bv = *(const bf16x8*)&Wl[wrow[nt]][k];
                if (ks & 1) a1[nt] = MFMA16(av, bv, a1[nt]);
                else        a0[nt] = MFMA16(av, bv, a0[nt]);
            }
        }
        if (quad == 0) {
            #pragma unroll
            for (int nt = 0; nt < 3; ++nt) {
                if (nt * 16 + n16 < RPB) {
                    f32x4 acc = a0[nt] + a1[nt];
                    #pragma unroll
                    for (int i = 0; i < 4; ++i) part[wvi][i][nt * 16 + n16] = acc[i];
                }
            }
        }
        __syncthreads();

        // ---- gates (48 threads, all wave 0) ----
        if (tid < 48) {
            float gr = 0.f, gz = 0.f, gn = 0.f;
            #pragma unroll
            for (int w4 = 0; w4 < 4; ++w4) {
                gr += part[w4][gb][ju];
                gz += part[w4][gb][12 + ju];
                gn += part[w4][gb][24 + ju];
            }
            float rr = 1.f / (1.f + __expf(-(xr + gr + bhr)));
            float zz = 1.f / (1.f + __expf(-(xz + gz + bhz)));
            float nn = tanhf(xn + rr * (gn + bhn));
            float hn = (1.f - zz) * nn + zz * hreg;
            hreg = hn;
            union { __bf16 h; unsigned short s; } cv;
            cv.h = (__bf16)hn;
            hpack[gb][ju] = cv.s;          // same-wave LDS exchange
            int uu = u0 + ju;
            out[((size_t)(gb * CN + uu / FN) * TN + t) * FN + (uu % FN)] = hn;
            if (ju % 3 == 0) {             // pack 3 units + tag, one u64 store
                int q = ju / 3;
                u64 p = (u64)hpack[gb][ju] | ((u64)hpack[gb][ju + 1] << 16) |
                        ((u64)hpack[gb][ju + 2] << 32) |
                        ((u64)(unsigned short)(t + 2) << 48);
                __hip_atomic_store(hbuf + (size_t)((t + 1) & 1) * 2048 + gb * 512 + blk * 4 + q,
                                   p, __ATOMIC_RELAXED, __HIP_MEMORY_SCOPE_AGENT);
            }
            // prefetch gx for step t+1 (off critical path)
            const __bf16* gnx = gxme + (size_t)(t + 1) * 144;
            xr = (float)gnx[0];
            xz = (float)gnx[12];
            xn = (float)gnx[24];
        }
        // no barrier: next poll self-synchronizes; hl overwrite is safe because
        // passing the poll implies every block (incl. ours) finished this step.
    }
    if (tid < 48) out[(size_t)BN * CN * TN * FN + gb * HID + u0 + ju] = hreg;
}

// =====================================================================
extern "C" void kernel_launch(void* const* d_in, const int* in_sizes, int n_in,
                              void* d_out, int out_size, void* d_ws, size_t ws_size,
                              hipStream_t stream) {
    const float* x   = (const float*)d_in[0];
    const float* h0  = (const float*)d_in[1];
    const float* Wq  = (const float*)d_in[2];
    const float* bq  = (const float*)d_in[3];
    const float* Wk  = (const float*)d_in[4];
    const float* bk  = (const float*)d_in[5];
    const float* Wv  = (const float*)d_in[6];
    const float* bv  = (const float*)d_in[7];
    const float* Wih = (const float*)d_in[8];
    const float* Whh = (const float*)d_in[9];
    const float* bih = (const float*)d_in[10];
    const float* bhh = (const float*)d_in[11];
    float* out = (float*)d_out;
    char* ws = (char*)d_ws;
    __bf16* seqB = (__bf16*)(ws + OFF_SEQ);
    __bf16* WihB = (__bf16*)(ws + OFF_WIH);
    __bf16* gxB  = (__bf16*)(ws + OFF_GX);
    u64*    hbuf = (u64*)(ws + OFF_H);

    hipLaunchKernelGGL(cvt_wih_kernel, dim3(2048), dim3(256), 0, stream, Wih, WihB);
    hipLaunchKernelGGL(conv_attn_kernel, dim3(4096), dim3(256), 0, stream,
                       x, Wq, bq, Wk, bk, Wv, bv, seqB);
    hipLaunchKernelGGL(gemm_kernel, dim3(36, 32), dim3(256), 0, stream, seqB, WihB, bih, gxB);

    void* args[] = {(void*)&gxB, (void*)&Whh, (void*)&bhh, (void*)&h0,
                    (void*)&hbuf, (void*)&out};
    hipLaunchCooperativeKernel((void*)gru_kernel, dim3(NB), dim3(256), args, 0, stream);
}